// Round 25
// baseline (47.395 us; speedup 1.0000x reference)
//
#include <hip/hip_runtime.h>
#include <hip/hip_bf16.h>
#include <stdint.h>

// Problem constants (fixed by the reference)
#define B_SZ 8192
#define D_SZ 256
#define R_SZ 8
#define N_SZ 1024
#define C_SZ (B_SZ / R_SZ)          // 1024
#define CN   (C_SZ * N_SZ)          // 1048576
#define L_SZ (B_SZ + 2 * R_SZ * CN) // 16785408 (logits length)

// i8 fixed-point: round(v*1792) = 128*H + L, |H|<=127, |L|<=64.
#define FP_SCALE 1792.0f
#define FP_INV_S2 3.113918e-7f   // 1/(1792^2)

typedef int   i32x4 __attribute__((ext_vector_type(4)));
typedef float f32x4 __attribute__((ext_vector_type(4)));

static __device__ __forceinline__ float sigmoidf_(float x) {
  return 1.0f / (1.0f + __expf(-x));
}
static __device__ __forceinline__ void gload16(const void* g, void* l) {
  __builtin_amdgcn_global_load_lds(
      (const __attribute__((address_space(1))) void*)g,
      (__attribute__((address_space(3))) void*)l, 16, 0, 0);
}

// ws layout (bytes): 4 i8 arrays, row stride 256B (natural row order i):
//   0   : lhs_H (2MB)
//   2MB : lhs_L
//   4MB : rhs_H
//   6MB : rhs_L

// ---------------------------------------------------------------------------
// Phase 1: F-reduce emb -> lhs/rhs, quantize to i8 digit pairs, pos logits.
// One wave per batch row i. 2048 blocks x 256 threads. (~7 us, BW-bound.)
// ---------------------------------------------------------------------------
__global__ __launch_bounds__(256) void prep_kernel(
    const float* __restrict__ emb, const float* __restrict__ trans,
    const int* __restrict__ rels, float* __restrict__ out,
    char* __restrict__ ws) {
  char* lhs_H = ws;
  char* lhs_L = ws + ((size_t)2 << 20);
  char* rhs_H = ws + ((size_t)4 << 20);
  char* rhs_L = ws + ((size_t)6 << 20);

  int wave = threadIdx.x >> 6;
  int lane = threadIdx.x & 63;
  int i = blockIdx.x * 4 + wave;            // 0..B-1

  const float4* emb4 = (const float4*)emb;  // emb row j = 128 float4 (F*D=512 f32)
  size_t bl = (size_t)(2 * i) * 128;
  size_t br = (size_t)(2 * i + 1) * 128;
  float4 a0 = emb4[bl + lane];
  float4 a1 = emb4[bl + 64 + lane];
  float4 b0 = emb4[br + lane];
  float4 b1 = emb4[br + 64 + lane];
  float lh[4] = {a0.x + a1.x, a0.y + a1.y, a0.z + a1.z, a0.w + a1.w};
  float rh[4] = {b0.x + b1.x, b0.y + b1.y, b0.z + b1.z, b0.w + b1.w};

  int rel = rels[i];
  float4 tv = ((const float4*)trans)[rel * 64 + lane];
  float tt[4] = {tv.x, tv.y, tv.z, tv.w};

  float p = 0.f;
#pragma unroll
  for (int j = 0; j < 4; ++j) p += lh[j] * (rh[j] + tt[j]);
#pragma unroll
  for (int off = 32; off; off >>= 1) p += __shfl_xor(p, off, 64);
  if (lane == 0) {
    out[i] = p;
    out[(size_t)L_SZ + i] = sigmoidf_(p);
  }

  // Quantize: t = clamp(v*1792); H = rn(t/128); L = rn(t) - 128H  (|L|<=64)
  int phL = 0, plL = 0, phR = 0, plR = 0;
#pragma unroll
  for (int j = 0; j < 4; ++j) {
    float t = fminf(fmaxf(lh[j] * FP_SCALE, -16256.f), 16256.f);
    int hi = __float2int_rn(t * 0.0078125f);
    int lo = __float2int_rn(t) - (hi << 7);
    phL |= (hi & 255) << (8 * j);
    plL |= (lo & 255) << (8 * j);
    t = fminf(fmaxf(rh[j] * FP_SCALE, -16256.f), 16256.f);
    hi = __float2int_rn(t * 0.0078125f);
    lo = __float2int_rn(t) - (hi << 7);
    phR |= (hi & 255) << (8 * j);
    plR |= (lo & 255) << (8 * j);
  }
  size_t rowb = (size_t)i * 256 + lane * 4;
  *(int*)(lhs_H + rowb) = phL;
  *(int*)(lhs_L + rowb) = plL;
  *(int*)(rhs_H + rowb) = phR;
  *(int*)(rhs_L + rowb) = plR;
}

// ---------------------------------------------------------------------------
// Phase 2: gather-GEMM negatives, i8 numerics, 64x64 tile, dbuf 32 KB LDS,
// (256,4) = 4 blocks/CU (R21/R24-proven). ONLY change vs R24: MFMA operands
// SWAPPED — mfma(b, a, acc) transposes C/D so acc[mi][ni][jj] =
// T[c = mi*16 + (lane&15)][n = ni*16 + (lane>>4)*4 + jj]: each lane holds 4
// consecutive output columns in registers -> direct f32x4 stores (8/lane vs
// 32 scalar; 1KB committed per instruction), no LDS round-trip (R19 lesson).
// mfma_i32_16x16x64_i8: acc1 += Hb*Ha ; acc2 += Lb*Ha + Hb*La  (transposed).
// logit = (16384*acc1 + 128*acc2) / 1792^2.
// ---------------------------------------------------------------------------
__global__ __launch_bounds__(256, 4) void negs_kernel(
    const char* __restrict__ ws,
    const int* __restrict__ order,
    const int* __restrict__ negL, const int* __restrict__ negR,
    float* __restrict__ out) {
  __shared__ char lds[2][16384];  // per buf: A_H@0 A_L@4K B_H@8K B_L@12K

  const char* lhs_H = ws;
  const char* lhs_L = ws + ((size_t)2 << 20);
  const char* rhs_H = ws + ((size_t)4 << 20);
  const char* rhs_L = ws + ((size_t)6 << 20);

  int hw = blockIdx.x;
  int bid = (hw & 7) * 512 + (hw >> 3);  // bijective: r == XCD (hw&7)
  int ntile = bid & 15;                   // 64-col tile
  int ctile = (bid >> 4) & 15;            // 64-row tile
  int side  = (bid >> 8) & 1;
  int r     = bid >> 9;

  int wave = threadIdx.x >> 6;
  int lane = threadIdx.x & 63;
  int wrow = wave >> 1, wcol = wave & 1;  // 2x2: 32 rows x 32 cols each
  int lx = lane & 15;
  int q = lane >> 4;                      // 16B chunk 0..3 within 64B row

  // side 0: A = s_rhs, B = samp_lhs ; side 1: A = s_lhs, B = samp_rhs
  const char* srcp;
  const int* idxp;
  int idxbase;
  if (wave < 2) {
    idxp = order;
    idxbase = r * C_SZ + ctile * 64;
    srcp = (wave == 0) ? (side ? lhs_H : rhs_H) : (side ? lhs_L : rhs_L);
  } else {
    idxp = side ? negR : negL;
    idxbase = r * N_SZ + ntile * 64;
    srcp = (wave == 2) ? (side ? rhs_H : lhs_H) : (side ? rhs_L : lhs_L);
  }
  int myoff = wave * 4096;

  // Staging map: load 'it' covers LDS rows it*16 + (lane>>2), chunk lane&3.
  // Source chunk inverse-swizzled: (lane&3) ^ ((row>>1)&3) = (lane&3)^((lane>>3)&3).
  unsigned srcswz = (unsigned)(((lane & 3) ^ ((lane >> 3) & 3)) << 4);
  unsigned goff[4];
#pragma unroll
  for (int it = 0; it < 4; ++it) {
    int grow = idxp[idxbase + it * 16 + (lane >> 2)];
    goff[it] = (unsigned)grow * 256u + srcswz;
  }

  i32x4 acc1[2][2] = {};  // Hb*Ha (transposed)
  i32x4 acc2[2][2] = {};  // Lb*Ha + Hb*La

  // Prologue: stage chunk 0 into buf 0.
#pragma unroll
  for (int it = 0; it < 4; ++it)
    gload16(srcp + goff[it], &lds[0][myoff] + it * 1024);
  __syncthreads();

#pragma unroll 1
  for (int kc = 0; kc < 4; ++kc) {
    // Early-issue next chunk's loads into the other buffer.
    if (kc < 3) {
      char* nl = &lds[(kc + 1) & 1][myoff];
#pragma unroll
      for (int it = 0; it < 4; ++it)
        gload16(srcp + goff[it] + (unsigned)(kc + 1) * 64u, nl + it * 1024);
    }

    const char* L0 = &lds[kc & 1][0];
    i32x4 ha[2], la[2], hb[2], lb[2];
#pragma unroll
    for (int mi = 0; mi < 2; ++mi) {
      int row = wrow * 32 + mi * 16 + lx;
      int off = row * 64 + ((q ^ ((row >> 1) & 3)) << 4);
      ha[mi] = *(const i32x4*)(L0 + off);
      la[mi] = *(const i32x4*)(L0 + 4096 + off);
    }
#pragma unroll
    for (int ni = 0; ni < 2; ++ni) {
      int row = wcol * 32 + ni * 16 + lx;
      int off = row * 64 + ((q ^ ((row >> 1) & 3)) << 4);
      hb[ni] = *(const i32x4*)(L0 + 8192 + off);
      lb[ni] = *(const i32x4*)(L0 + 12288 + off);
    }
    // Swapped operands: D = B-frag x A-frag -> transposed C/D mapping.
#pragma unroll
    for (int mi = 0; mi < 2; ++mi)
#pragma unroll
      for (int ni = 0; ni < 2; ++ni) {
        acc1[mi][ni] = __builtin_amdgcn_mfma_i32_16x16x64_i8(hb[ni], ha[mi], acc1[mi][ni], 0, 0, 0);
        acc2[mi][ni] = __builtin_amdgcn_mfma_i32_16x16x64_i8(hb[ni], la[mi], acc2[mi][ni], 0, 0, 0);
        acc2[mi][ni] = __builtin_amdgcn_mfma_i32_16x16x64_i8(lb[ni], ha[mi], acc2[mi][ni], 0, 0, 0);
      }

    __syncthreads();
  }

  // Epilogue: transposed C/D -> acc[mi][ni][jj] = T[c = mi*16+lx]
  // [n = ni*16 + q*4 + jj]. Each lane stores f32x4 (4 consecutive cols of
  // one row) — 8 wide stores/lane, no LDS redistribution.
  size_t obase = (size_t)B_SZ + ((size_t)(r * 2 + side)) * CN;
  int gc0 = ntile * 64 + wcol * 32 + (q << 2);
#pragma unroll
  for (int mi = 0; mi < 2; ++mi) {
    int gr = ctile * 64 + wrow * 32 + mi * 16 + lx;
    size_t rowb = obase + (size_t)gr * N_SZ;
#pragma unroll
    for (int ni = 0; ni < 2; ++ni) {
      f32x4 v, s;
#pragma unroll
      for (int jj = 0; jj < 4; ++jj) {
        v[jj] = fmaf(16384.0f, (float)acc1[mi][ni][jj],
                     128.0f * (float)acc2[mi][ni][jj]) * FP_INV_S2;
        s[jj] = sigmoidf_(v[jj]);
      }
      size_t idx = rowb + gc0 + ni * 16;
      *(f32x4*)(out + idx) = v;
      *(f32x4*)(out + (size_t)L_SZ + idx) = s;
    }
  }
}

// ---------------------------------------------------------------------------
extern "C" void kernel_launch(void* const* d_in, const int* in_sizes, int n_in,
                              void* d_out, int out_size, void* d_ws, size_t ws_size,
                              hipStream_t stream) {
  const float* emb   = (const float*)d_in[0];
  const float* trans = (const float*)d_in[1];
  const int*   rels  = (const int*)d_in[2];
  const int*   order = (const int*)d_in[3];
  const int*   negL  = (const int*)d_in[4];
  const int*   negR  = (const int*)d_in[5];
  float* out = (float*)d_out;
  char* ws = (char*)d_ws;  // 8 MB of i8 digit arrays

  prep_kernel<<<B_SZ / 4, 256, 0, stream>>>(emb, trans, rels, out, ws);
  negs_kernel<<<4096, 256, 0, stream>>>(ws, order, negL, negR, out);
}

// Round 26
// 42.512 us; speedup vs baseline: 1.1149x; 1.1149x over previous
//
#include <hip/hip_runtime.h>
#include <hip/hip_bf16.h>
#include <stdint.h>

// Problem constants (fixed by the reference)
#define B_SZ 8192
#define D_SZ 256
#define R_SZ 8
#define N_SZ 1024
#define C_SZ (B_SZ / R_SZ)          // 1024
#define CN   (C_SZ * N_SZ)          // 1048576
#define L_SZ (B_SZ + 2 * R_SZ * CN) // 16785408 (logits length)

// i8 fixed-point: round(v*1792) = 128*H + L, |H|<=127, |L|<=64.
#define FP_SCALE 1792.0f
#define FP_INV_S2 3.113918e-7f   // 1/(1792^2)

typedef int   i32x4 __attribute__((ext_vector_type(4)));
typedef float f32x4 __attribute__((ext_vector_type(4)));

static __device__ __forceinline__ float sigmoidf_(float x) {
  return 1.0f / (1.0f + __expf(-x));
}
static __device__ __forceinline__ void gload16(const void* g, void* l) {
  __builtin_amdgcn_global_load_lds(
      (const __attribute__((address_space(1))) void*)g,
      (__attribute__((address_space(3))) void*)l, 16, 0, 0);
}

// ws layout (bytes): 4 i8 arrays, row stride 256B (natural row order i):
//   0   : lhs_H (2MB)
//   2MB : lhs_L
//   4MB : rhs_H
//   6MB : rhs_L

// ---------------------------------------------------------------------------
// Phase 1: F-reduce emb -> lhs/rhs, quantize to i8 digit pairs, pos logits.
// One wave per batch row i. 2048 blocks x 256 threads. (~7 us, BW-bound.)
// ---------------------------------------------------------------------------
__global__ __launch_bounds__(256) void prep_kernel(
    const float* __restrict__ emb, const float* __restrict__ trans,
    const int* __restrict__ rels, float* __restrict__ out,
    char* __restrict__ ws) {
  char* lhs_H = ws;
  char* lhs_L = ws + ((size_t)2 << 20);
  char* rhs_H = ws + ((size_t)4 << 20);
  char* rhs_L = ws + ((size_t)6 << 20);

  int wave = threadIdx.x >> 6;
  int lane = threadIdx.x & 63;
  int i = blockIdx.x * 4 + wave;            // 0..B-1

  const float4* emb4 = (const float4*)emb;  // emb row j = 128 float4 (F*D=512 f32)
  size_t bl = (size_t)(2 * i) * 128;
  size_t br = (size_t)(2 * i + 1) * 128;
  float4 a0 = emb4[bl + lane];
  float4 a1 = emb4[bl + 64 + lane];
  float4 b0 = emb4[br + lane];
  float4 b1 = emb4[br + 64 + lane];
  float lh[4] = {a0.x + a1.x, a0.y + a1.y, a0.z + a1.z, a0.w + a1.w};
  float rh[4] = {b0.x + b1.x, b0.y + b1.y, b0.z + b1.z, b0.w + b1.w};

  int rel = rels[i];
  float4 tv = ((const float4*)trans)[rel * 64 + lane];
  float tt[4] = {tv.x, tv.y, tv.z, tv.w};

  float p = 0.f;
#pragma unroll
  for (int j = 0; j < 4; ++j) p += lh[j] * (rh[j] + tt[j]);
#pragma unroll
  for (int off = 32; off; off >>= 1) p += __shfl_xor(p, off, 64);
  if (lane == 0) {
    out[i] = p;
    out[(size_t)L_SZ + i] = sigmoidf_(p);
  }

  // Quantize: t = clamp(v*1792); H = rn(t/128); L = rn(t) - 128H  (|L|<=64)
  int phL = 0, plL = 0, phR = 0, plR = 0;
#pragma unroll
  for (int j = 0; j < 4; ++j) {
    float t = fminf(fmaxf(lh[j] * FP_SCALE, -16256.f), 16256.f);
    int hi = __float2int_rn(t * 0.0078125f);
    int lo = __float2int_rn(t) - (hi << 7);
    phL |= (hi & 255) << (8 * j);
    plL |= (lo & 255) << (8 * j);
    t = fminf(fmaxf(rh[j] * FP_SCALE, -16256.f), 16256.f);
    hi = __float2int_rn(t * 0.0078125f);
    lo = __float2int_rn(t) - (hi << 7);
    phR |= (hi & 255) << (8 * j);
    plR |= (lo & 255) << (8 * j);
  }
  size_t rowb = (size_t)i * 256 + lane * 4;
  *(int*)(lhs_H + rowb) = phL;
  *(int*)(lhs_L + rowb) = plL;
  *(int*)(rhs_H + rowb) = phR;
  *(int*)(rhs_L + rowb) = plR;
}

// ---------------------------------------------------------------------------
// Phase 2: gather-GEMM negatives, i8 numerics, 64x64 tile -> 16 KB/buf LDS,
// dbuf 32 KB; launch_bounds(256,4) -> 4 blocks/CU (measured best: R21/R24).
// 4096 blocks; r == XCD bijective swizzle. R15 early-issue dbuf schedule
// (one __syncthreads per K-chunk); R17 row-grouped plain-store epilogue.
// Staging symmetric: wave w stages array w (A_H/A_L/B_H/B_L, 4KB, 4 gload16).
// Wave grid 2x2: 32x32 quadrant (acc1+acc2 = 32 VGPR).
// mfma_i32_16x16x64_i8: acc1 += Ha*Hb ; acc2 += La*Hb + Ha*Lb.
// logit = (16384*acc1 + 128*acc2) / 1792^2.
// ---------------------------------------------------------------------------
__global__ __launch_bounds__(256, 4) void negs_kernel(
    const char* __restrict__ ws,
    const int* __restrict__ order,
    const int* __restrict__ negL, const int* __restrict__ negR,
    float* __restrict__ out) {
  __shared__ char lds[2][16384];  // per buf: A_H@0 A_L@4K B_H@8K B_L@12K

  const char* lhs_H = ws;
  const char* lhs_L = ws + ((size_t)2 << 20);
  const char* rhs_H = ws + ((size_t)4 << 20);
  const char* rhs_L = ws + ((size_t)6 << 20);

  int hw = blockIdx.x;
  int bid = (hw & 7) * 512 + (hw >> 3);  // bijective: r == XCD (hw&7)
  int ntile = bid & 15;                   // 64-col tile
  int ctile = (bid >> 4) & 15;            // 64-row tile
  int side  = (bid >> 8) & 1;
  int r     = bid >> 9;

  int wave = threadIdx.x >> 6;
  int lane = threadIdx.x & 63;
  int wrow = wave >> 1, wcol = wave & 1;  // 2x2: 32 rows x 32 cols each
  int lx = lane & 15;
  int q = lane >> 4;                      // 16B chunk 0..3 within 64B row

  // side 0: A = s_rhs, B = samp_lhs ; side 1: A = s_lhs, B = samp_rhs
  const char* srcp;
  const int* idxp;
  int idxbase;
  if (wave < 2) {
    idxp = order;
    idxbase = r * C_SZ + ctile * 64;
    srcp = (wave == 0) ? (side ? lhs_H : rhs_H) : (side ? lhs_L : rhs_L);
  } else {
    idxp = side ? negR : negL;
    idxbase = r * N_SZ + ntile * 64;
    srcp = (wave == 2) ? (side ? rhs_H : lhs_H) : (side ? rhs_L : lhs_L);
  }
  int myoff = wave * 4096;

  // Staging map: load 'it' covers LDS rows it*16 + (lane>>2), chunk lane&3.
  // Source chunk inverse-swizzled: (lane&3) ^ ((row>>1)&3) = (lane&3)^((lane>>3)&3).
  unsigned srcswz = (unsigned)(((lane & 3) ^ ((lane >> 3) & 3)) << 4);
  unsigned goff[4];
#pragma unroll
  for (int it = 0; it < 4; ++it) {
    int grow = idxp[idxbase + it * 16 + (lane >> 2)];
    goff[it] = (unsigned)grow * 256u + srcswz;
  }

  i32x4 acc1[2][2] = {};  // Ha*Hb
  i32x4 acc2[2][2] = {};  // La*Hb + Ha*Lb

  // Prologue: stage chunk 0 into buf 0.
#pragma unroll
  for (int it = 0; it < 4; ++it)
    gload16(srcp + goff[it], &lds[0][myoff] + it * 1024);
  __syncthreads();

#pragma unroll 1
  for (int kc = 0; kc < 4; ++kc) {
    // Early-issue next chunk's loads into the other buffer.
    if (kc < 3) {
      char* nl = &lds[(kc + 1) & 1][myoff];
#pragma unroll
      for (int it = 0; it < 4; ++it)
        gload16(srcp + goff[it] + (unsigned)(kc + 1) * 64u, nl + it * 1024);
    }

    const char* L0 = &lds[kc & 1][0];
    i32x4 ha[2], la[2], hb[2], lb[2];
#pragma unroll
    for (int mi = 0; mi < 2; ++mi) {
      int row = wrow * 32 + mi * 16 + lx;
      int off = row * 64 + ((q ^ ((row >> 1) & 3)) << 4);
      ha[mi] = *(const i32x4*)(L0 + off);
      la[mi] = *(const i32x4*)(L0 + 4096 + off);
    }
#pragma unroll
    for (int ni = 0; ni < 2; ++ni) {
      int row = wcol * 32 + ni * 16 + lx;
      int off = row * 64 + ((q ^ ((row >> 1) & 3)) << 4);
      hb[ni] = *(const i32x4*)(L0 + 8192 + off);
      lb[ni] = *(const i32x4*)(L0 + 12288 + off);
    }
#pragma unroll
    for (int mi = 0; mi < 2; ++mi)
#pragma unroll
      for (int ni = 0; ni < 2; ++ni) {
        acc1[mi][ni] = __builtin_amdgcn_mfma_i32_16x16x64_i8(ha[mi], hb[ni], acc1[mi][ni], 0, 0, 0);
        acc2[mi][ni] = __builtin_amdgcn_mfma_i32_16x16x64_i8(la[mi], hb[ni], acc2[mi][ni], 0, 0, 0);
        acc2[mi][ni] = __builtin_amdgcn_mfma_i32_16x16x64_i8(ha[mi], lb[ni], acc2[mi][ni], 0, 0, 0);
      }

    __syncthreads();
  }

  // Epilogue: per output row, this wave's 2 stores covering its contiguous
  // 128B cache line issue back-to-back (plain stores; R17-proven ordering).
  // C/D layout: col = lane&15, row = (lane>>4)*4 + jj.
  size_t obase = (size_t)B_SZ + ((size_t)(r * 2 + side)) * CN;
  int gcb = ntile * 64 + wcol * 32 + lx;
  int grb = ctile * 64 + wrow * 32 + ((lane >> 4) << 2);
#pragma unroll
  for (int mi = 0; mi < 2; ++mi) {
#pragma unroll
    for (int jj = 0; jj < 4; ++jj) {
      int gr = grb + mi * 16 + jj;
      size_t rowb = obase + (size_t)gr * N_SZ;
      float v[2], s[2];
#pragma unroll
      for (int ni = 0; ni < 2; ++ni) {
        v[ni] = fmaf(16384.0f, (float)acc1[mi][ni][jj],
                     128.0f * (float)acc2[mi][ni][jj]) * FP_INV_S2;
        s[ni] = sigmoidf_(v[ni]);
      }
#pragma unroll
      for (int ni = 0; ni < 2; ++ni)
        out[rowb + gcb + ni * 16] = v[ni];
#pragma unroll
      for (int ni = 0; ni < 2; ++ni)
        out[(size_t)L_SZ + rowb + gcb + ni * 16] = s[ni];
    }
  }
}

// ---------------------------------------------------------------------------
extern "C" void kernel_launch(void* const* d_in, const int* in_sizes, int n_in,
                              void* d_out, int out_size, void* d_ws, size_t ws_size,
                              hipStream_t stream) {
  const float* emb   = (const float*)d_in[0];
  const float* trans = (const float*)d_in[1];
  const int*   rels  = (const int*)d_in[2];
  const int*   order = (const int*)d_in[3];
  const int*   negL  = (const int*)d_in[4];
  const int*   negR  = (const int*)d_in[5];
  float* out = (float*)d_out;
  char* ws = (char*)d_ws;  // 8 MB of i8 digit arrays

  prep_kernel<<<B_SZ / 4, 256, 0, stream>>>(emb, trans, rels, out, ws);
  negs_kernel<<<4096, 256, 0, stream>>>(ws, order, negL, negR, out);
}